// Round 1
// baseline (2321.183 us; speedup 1.0000x reference)
//
#include <hip/hip_runtime.h>
#include <math.h>

// ---------------------------------------------------------------------------
// FRU cell, decomposed:
//   state[f,s](t) = sum_{tau<=t} c_f(tau)*stats[s](tau)   (f>=1; f=0: current only)
//   c_f(t) = (1/L)*cos((2pi/L)*t*f + 2pi*phases[f])
// Scan only carries: Pa[r] = state_acc@Wr  (64 floats) and stats(t-1) (64 floats).
//   recur(t)  = gelu(Pa(t-1) + c0*stats(t-1)@Wr0 + br)
//   stats(t)  = gelu(xstat[b,t] + recur@Wsr + bs)
//   Pa(t)     = Pa(t-1) + stats(t)@M_t,  M_t precomputed (bf16, streamed)
// Then: state materialized bf16 (cumsum over t), out = gelu(state@Wo + bo) as
// one big bf16 MFMA GEMM.
// ---------------------------------------------------------------------------

#define TWO_PI 6.283185307179586f
#define INV_L  (1.0f/2048.0f)

typedef unsigned short u16;
typedef __attribute__((ext_vector_type(8))) short bf16x8;   // 8 bf16 = 4 VGPRs
typedef __attribute__((ext_vector_type(4))) float f32x4;

__device__ __forceinline__ float bf2f(u16 u){ return __uint_as_float(((unsigned int)u) << 16); }
__device__ __forceinline__ u16 f2bf(float x){
  unsigned int u = __float_as_uint(x);
  u += 0x7FFFu + ((u >> 16) & 1u);           // round-to-nearest-even
  return (u16)(u >> 16);
}
__device__ __forceinline__ float gelu_tanh(float x){
  // tanh-approx gelu: error <3e-4 abs; attenuated ~50x through the (1/L) cumsum.
  float y = 0.7978845608028654f * x * (1.0f + 0.044715f * x * x);
  y = fminf(fmaxf(y, -12.0f), 12.0f);
  float e = __expf(2.0f * y);
  float th = (e - 1.0f) / (e + 1.0f);
  return 0.5f * x * (1.0f + th);
}
__device__ __forceinline__ float gelu_erf(float x){
  return 0.5f * x * (1.0f + erff(x * 0.7071067811865475f));
}

// --------------------------- K2: M_t + ctab precompute ----------------------
// MT[slot=t-1][r][s] (bf16) = sum_{f=1..15} c_f(t) * Wr[(f*64+s)*64 + r]
// ctab[t][f] = c_f(t), t in [1,2048]
__global__ __launch_bounds__(256) void k_mprep(const float* __restrict__ Wr,
    const float* __restrict__ phases, u16* __restrict__ MT, float* __restrict__ ctab){
  int slot = blockIdx.x;                 // tau = slot+1
  float tau = (float)(slot + 1);
  __shared__ float cf[16];
  int tid = threadIdx.x;
  if (tid < 16){
    float c = INV_L * cosf((TWO_PI * INV_L) * tau * (float)tid + TWO_PI * phases[tid]);
    cf[tid] = c;
    ctab[(slot + 1) * 16 + tid] = c;
  }
  __syncthreads();
  int r = tid & 63, s0 = (tid >> 6) * 16;
  float acc[16];
#pragma unroll
  for (int i = 0; i < 16; ++i) acc[i] = 0.0f;
  for (int f = 1; f < 16; ++f){
    float c = cf[f];
    const float* wp = Wr + (f * 64 + s0) * 64 + r;   // coalesced over r (lanes)
#pragma unroll
    for (int i = 0; i < 16; ++i) acc[i] += c * wp[i * 64];
  }
  u16* o = MT + ((size_t)slot * 64 + r) * 64 + s0;
  uint4 p0, p1;
  p0.x = (unsigned)f2bf(acc[0])  | ((unsigned)f2bf(acc[1])  << 16);
  p0.y = (unsigned)f2bf(acc[2])  | ((unsigned)f2bf(acc[3])  << 16);
  p0.z = (unsigned)f2bf(acc[4])  | ((unsigned)f2bf(acc[5])  << 16);
  p0.w = (unsigned)f2bf(acc[6])  | ((unsigned)f2bf(acc[7])  << 16);
  p1.x = (unsigned)f2bf(acc[8])  | ((unsigned)f2bf(acc[9])  << 16);
  p1.y = (unsigned)f2bf(acc[10]) | ((unsigned)f2bf(acc[11]) << 16);
  p1.z = (unsigned)f2bf(acc[12]) | ((unsigned)f2bf(acc[13]) << 16);
  p1.w = (unsigned)f2bf(acc[14]) | ((unsigned)f2bf(acc[15]) << 16);
  ((uint4*)o)[0] = p0;
  ((uint4*)o)[1] = p1;
}

// --------------------------- K1: xstat = x @ Ws[0:128,:] --------------------
__global__ __launch_bounds__(256) void k_xstat(const float* __restrict__ x,
    const float* __restrict__ Ws, float* __restrict__ xstat){
  __shared__ float4 xt4[64 * 32];        // 64 rows x 128 cols
  __shared__ float partial[4][64];
  int tid = threadIdx.x;
  int row0 = blockIdx.x * 64;
  const float4* xg = (const float4*)(x + (size_t)row0 * 128);
  for (int i = tid; i < 2048; i += 256) xt4[i] = xg[i];
  int s = tid & 63, kq = tid >> 6;       // K split 4 x 32
  float wk[32];
#pragma unroll
  for (int j = 0; j < 32; ++j) wk[j] = Ws[(kq * 32 + j) * 64 + s];
  __syncthreads();
  for (int rr = 0; rr < 64; ++rr){
    const float4* xr = &xt4[rr * 32 + kq * 8];
    float a = 0.0f;
#pragma unroll
    for (int j = 0; j < 8; ++j){
      float4 v = xr[j];
      a += v.x * wk[j*4] + v.y * wk[j*4+1] + v.z * wk[j*4+2] + v.w * wk[j*4+3];
    }
    partial[kq][s] = a;
    __syncthreads();
    if (tid < 64)
      xstat[(size_t)(row0 + rr) * 64 + tid] =
        partial[0][tid] + partial[1][tid] + partial[2][tid] + partial[3][tid];
    __syncthreads();
  }
}

// --------------------------- K4b: WoT[n][k] = bf16(Wo[k][n]) ----------------
__global__ __launch_bounds__(256) void k_wot(const float* __restrict__ Wo, u16* __restrict__ WoT){
  __shared__ float tile[64][65];
  int bx = blockIdx.x & 15, by = blockIdx.x >> 4;
  int k0 = bx * 64, n0 = by * 64;
  int tid = threadIdx.x, ln = tid & 63, w = tid >> 6;
#pragma unroll
  for (int i = 0; i < 16; ++i){
    int kk = w * 16 + i;
    tile[kk][ln] = Wo[(size_t)(k0 + kk) * 1024 + n0 + ln];
  }
  __syncthreads();
#pragma unroll
  for (int i = 0; i < 16; ++i){
    int nn = w * 16 + i;
    WoT[(size_t)(n0 + nn) * 1024 + k0 + ln] = f2bf(tile[ln][nn]);
  }
}

// --------------------------- K3: the sequential scan ------------------------
// One workgroup per batch element. 256 threads: idx = w*16 + (l>>2) is the
// output index (r in stage A, s in stage B); q = l&3 splits K=64 into 4x16,
// reduced with __shfl_xor within the quad (no barrier).
__global__ __launch_bounds__(256) void k_scan(
    const float* __restrict__ Wr, const float* __restrict__ br,
    const float* __restrict__ Ws, const float* __restrict__ bs,
    const float* __restrict__ phases, const float* __restrict__ xstat,
    const u16* __restrict__ MT, float* __restrict__ statsbuf){
  int b = blockIdx.x;
  int tid = threadIdx.x;
  int w = tid >> 6, l = tid & 63;
  int idx = w * 16 + (l >> 2);
  int q = l & 3;
  __shared__ float4 sprev4[16];
  __shared__ float4 recur4[16];
  float* sprev  = (float*)sprev4;
  float* recurs = (float*)recur4;
  float wr0[16], wsr[16];
#pragma unroll
  for (int i = 0; i < 16; ++i) wr0[i] = Wr[(q * 16 + i) * 64 + idx];          // Wr rows f=0
#pragma unroll
  for (int i = 0; i < 16; ++i) wsr[i] = Ws[(128 + q * 16 + i) * 64 + idx];    // Ws rows 128..191
  float br_r = br[idx];
  float bs_s = bs[idx];
  float c0 = INV_L * cosf(TWO_PI * phases[0]);
  float Pa = 0.0f;
  if (tid < 64) sprev[tid] = 0.0f;
  const uint4* mt4 = (const uint4*)MT;       // 512 uint4 per slot
  int moff = idx * 8 + q * 2;
  uint4 m0v = mt4[moff];                     // slot 0 (used at t=1 where sprev=0)
  uint4 m1v = mt4[moff + 1];
  const float* xsp = xstat + (size_t)b * 2048 * 64;
  float xs_cur = xsp[idx];                   // t=1
  float* sb = statsbuf + (size_t)b * 2048 * 64;
  __syncthreads();
  for (int t = 1; t <= 2048; ++t){
    // prefetch next step's M row-block (slot t-1, used at step t+1) and xstat
    int nslot = t - 1;
    uint4 n0v = mt4[(size_t)nslot * 512 + moff];
    uint4 n1v = mt4[(size_t)nslot * 512 + moff + 1];
    int nx = (t < 2048) ? t : 2047;
    float xs_nxt = xsp[(size_t)nx * 64 + idx];
    // unpack current M (bf16 -> f32)
    union { uint4 v; u16 h[8]; } ua, ub;
    ua.v = m0v; ub.v = m1v;
    float mv[16];
#pragma unroll
    for (int i = 0; i < 8; ++i){ mv[i] = bf2f(ua.h[i]); mv[8 + i] = bf2f(ub.h[i]); }
    // Stage A: d1 = sprev@M_{t-1}, d2 = sprev@Wr0
    float d1 = 0.0f, d2 = 0.0f;
#pragma unroll
    for (int j = 0; j < 4; ++j){
      float4 sv = sprev4[q * 4 + j];
      d1 += sv.x*mv[j*4] + sv.y*mv[j*4+1] + sv.z*mv[j*4+2] + sv.w*mv[j*4+3];
      d2 += sv.x*wr0[j*4] + sv.y*wr0[j*4+1] + sv.z*wr0[j*4+2] + sv.w*wr0[j*4+3];
    }
    d1 += __shfl_xor(d1, 1); d1 += __shfl_xor(d1, 2);
    d2 += __shfl_xor(d2, 1); d2 += __shfl_xor(d2, 2);
    Pa += d1;                                  // Pa = P_acc(t-1)
    float rp = Pa + c0 * d2 + br_r;
    float rec = gelu_tanh(rp);
    if (q == 0) recurs[idx] = rec;
    __syncthreads();
    // Stage B: stats = gelu(xstat + recur@Wsr + bs)
    float a2 = 0.0f;
#pragma unroll
    for (int j = 0; j < 4; ++j){
      float4 rv = recur4[q * 4 + j];
      a2 += rv.x*wsr[j*4] + rv.y*wsr[j*4+1] + rv.z*wsr[j*4+2] + rv.w*wsr[j*4+3];
    }
    a2 += __shfl_xor(a2, 1); a2 += __shfl_xor(a2, 2);
    float spre = a2 + xs_cur + bs_s;
    float stt = gelu_tanh(spre);
    if (q == 0){ sprev[idx] = stt; sb[(size_t)(t - 1) * 64 + idx] = stt; }
    __syncthreads();
    m0v = n0v; m1v = n1v; xs_cur = xs_nxt;
  }
}

// --------------------------- K4: state materialization (bf16) ---------------
// state[b,t,f*64+s]: f>=1 cumsum of c_f(t)*stats; f=0 current term only.
__global__ __launch_bounds__(256) void k_state(const float* __restrict__ statsbuf,
    const float* __restrict__ ctab, u16* __restrict__ stateA){
  int g = blockIdx.x * 256 + threadIdx.x;       // [0, 32768)
  int s = g & 63, f = (g >> 6) & 15, b = g >> 10;
  const float* sp = statsbuf + (size_t)b * 2048 * 64 + s;
  u16* op = stateA + (size_t)b * 2048 * 1024 + f * 64 + s;
  float acc = 0.0f;
  const bool f0 = (f == 0);
  for (int t0 = 0; t0 < 2048; t0 += 8){
    float sv[8], cv[8];
#pragma unroll
    for (int i = 0; i < 8; ++i) sv[i] = sp[(size_t)(t0 + i) * 64];
#pragma unroll
    for (int i = 0; i < 8; ++i) cv[i] = ctab[(t0 + i + 1) * 16 + f];
#pragma unroll
    for (int i = 0; i < 8; ++i){
      acc = f0 ? (cv[i] * sv[i]) : fmaf(cv[i], sv[i], acc);
      op[(size_t)(t0 + i) * 1024] = f2bf(acc);
    }
  }
}

// --------------------------- K5: out = gelu(state @ Wo + bo) ----------------
// bf16 MFMA GEMM, 128x128 tile, 4 waves, 16x16x32, BT layout in LDS.
__global__ __launch_bounds__(256) void k_gemm(const u16* __restrict__ A,
    const u16* __restrict__ Bt, const float* __restrict__ bo, float* __restrict__ out){
  int nt = blockIdx.x & 7, mt = blockIdx.x >> 3;
  int m0 = mt * 128, n0 = nt * 128;
  __shared__ __align__(16) u16 As[128 * 32];
  __shared__ __align__(16) u16 Bs[128 * 32];
  int tid = threadIdx.x;
  int w = tid >> 6, l = tid & 63;
  int mh = (w & 1) * 64, nh = (w >> 1) * 64;
  int lr = l & 15, lq = l >> 4;
  f32x4 acc[4][4] = {};
  for (int k0 = 0; k0 < 1024; k0 += 32){
    int c = tid;
#pragma unroll
    for (int rr = 0; rr < 2; ++rr, c += 256){
      int row = c >> 2, qq = c & 3;
      *((uint4*)&As[row * 32 + qq * 8]) = *(const uint4*)(A  + (size_t)(m0 + row) * 1024 + k0 + qq * 8);
      *((uint4*)&Bs[row * 32 + qq * 8]) = *(const uint4*)(Bt + (size_t)(n0 + row) * 1024 + k0 + qq * 8);
    }
    __syncthreads();
    bf16x8 af[4], bfr[4];
#pragma unroll
    for (int i = 0; i < 4; ++i) af[i]  = *(const bf16x8*)&As[(mh + i * 16 + lr) * 32 + lq * 8];
#pragma unroll
    for (int i = 0; i < 4; ++i) bfr[i] = *(const bf16x8*)&Bs[(nh + i * 16 + lr) * 32 + lq * 8];
#pragma unroll
    for (int i = 0; i < 4; ++i)
#pragma unroll
      for (int j = 0; j < 4; ++j)
        acc[i][j] = __builtin_amdgcn_mfma_f32_16x16x32_bf16(af[i], bfr[j], acc[i][j], 0, 0, 0);
    __syncthreads();
  }
#pragma unroll
  for (int i = 0; i < 4; ++i){
#pragma unroll
    for (int j = 0; j < 4; ++j){
      int n = n0 + nh + j * 16 + lr;
      float bias = bo[n];
#pragma unroll
      for (int rg = 0; rg < 4; ++rg){
        int m = m0 + mh + i * 16 + lq * 4 + rg;
        out[(size_t)m * 1024 + n] = gelu_erf(acc[i][j][rg] + bias);
      }
    }
  }
}

// --------------------------- launcher ---------------------------------------
extern "C" void kernel_launch(void* const* d_in, const int* in_sizes, int n_in,
                              void* d_out, int out_size, void* d_ws, size_t ws_size,
                              hipStream_t stream){
  const float* x  = (const float*)d_in[0];
  const float* Wr = (const float*)d_in[1];
  const float* br = (const float*)d_in[2];
  const float* Ws = (const float*)d_in[3];
  const float* bs = (const float*)d_in[4];
  const float* Wo = (const float*)d_in[5];
  const float* bo = (const float*)d_in[6];
  const float* ph = (const float*)d_in[7];
  float* out = (float*)d_out;

  char* wp = (char*)d_ws;
  float* xstat    = (float*)(wp);                     // 16 MB: 65536 x 64 f32
  float* statsbuf = (float*)(wp + 16777216);          // 16 MB: 32 x 2048 x 64 f32
  u16*   MT       = (u16*)  (wp + 33554432);          // 16 MB: 2048 x 64 x 64 bf16
  float* ctab     = (float*)(wp + 50331648);          // 128 KB: 2049 x 16 f32
  u16*   WoT      = (u16*)  (wp + 50593792);          // 2 MB: 1024 x 1024 bf16
  u16*   stateA   = (u16*)  (wp + 52690944);          // 128 MB: 65536 x 1024 bf16

  hipLaunchKernelGGL(k_mprep, dim3(2048), dim3(256), 0, stream, Wr, ph, MT, ctab);
  hipLaunchKernelGGL(k_xstat, dim3(1024), dim3(256), 0, stream, x, Ws, xstat);
  hipLaunchKernelGGL(k_wot,   dim3(256),  dim3(256), 0, stream, Wo, WoT);
  hipLaunchKernelGGL(k_scan,  dim3(32),   dim3(256), 0, stream, Wr, br, Ws, bs, ph, xstat, MT, statsbuf);
  hipLaunchKernelGGL(k_state, dim3(128),  dim3(256), 0, stream, statsbuf, ctab, stateA);
  hipLaunchKernelGGL(k_gemm,  dim3(4096), dim3(256), 0, stream, stateA, WoT, bo, out);
}